// Round 4
// baseline (2006.655 us; speedup 1.0000x reference)
//
#include <hip/hip_runtime.h>
#include <hip/hip_bf16.h>

#define S_ 512
#define B_ 32
#define D_ 512
#define H_ 8
#define L_ 6
#define DFF_ 1024
#define M_ (B_*S_)   // 16384 rows

typedef __attribute__((ext_vector_type(8))) short bf16x8;
typedef __attribute__((ext_vector_type(4))) float f32x4;

__device__ __forceinline__ ushort f2bf(float f) {
  union { float f; unsigned int u; } x; x.f = f;
  unsigned int r = x.u + 0x7fffu + ((x.u >> 16) & 1u);
  return (ushort)(r >> 16);
}
__device__ __forceinline__ float bf2f(unsigned int u) {
  union { unsigned int u; float f; } x; x.u = u << 16;
  return x.f;
}

__device__ __forceinline__ void gload16(const ushort* g, ushort* l) {
  __builtin_amdgcn_global_load_lds(
      (const __attribute__((address_space(1))) unsigned int*)g,
      (__attribute__((address_space(3))) unsigned int*)l, 16, 0, 0);
}

// ---------------------------------------------------------------------------
// f32 -> bf16 bulk convert
__global__ __launch_bounds__(256) void cvt_bf16(const float* __restrict__ in,
    ushort* __restrict__ out, int n8)
{
  int t = blockIdx.x * 256 + threadIdx.x;
  if (t >= n8) return;
  const float4* p = (const float4*)(in + (size_t)t * 8);
  float4 v0 = p[0], v1 = p[1];
  uint4 w;
  w.x = (unsigned)f2bf(v0.x) | ((unsigned)f2bf(v0.y) << 16);
  w.y = (unsigned)f2bf(v0.z) | ((unsigned)f2bf(v0.w) << 16);
  w.z = (unsigned)f2bf(v1.x) | ((unsigned)f2bf(v1.y) << 16);
  w.w = (unsigned)f2bf(v1.z) | ((unsigned)f2bf(v1.w) << 16);
  *(uint4*)(out + (size_t)t * 8) = w;
}

// ---------------------------------------------------------------------------
// Gather embedding rows into bf16 A matrix [16384][1024]
__global__ __launch_bounds__(256) void gather_emb(const int* __restrict__ x,
    const float* __restrict__ arg_emb, ushort* __restrict__ Ag)
{
  int t = blockIdx.x * 256 + threadIdx.x;
  size_t base = (size_t)t * 8;
  int m = (int)(base >> 10), kk = (int)(base & 1023);
  int j = kk >> 7, c = kk & 127;
  int b = m >> 9, s = m & 511;
  int a = x[(size_t)(s * B_ + b) * 9 + 1 + j];
  const float4* p = (const float4*)(arg_emb + (size_t)a * 128 + c);
  float4 v0 = p[0], v1 = p[1];
  uint4 w;
  w.x = (unsigned)f2bf(v0.x) | ((unsigned)f2bf(v0.y) << 16);
  w.y = (unsigned)f2bf(v0.z) | ((unsigned)f2bf(v0.w) << 16);
  w.z = (unsigned)f2bf(v1.x) | ((unsigned)f2bf(v1.y) << 16);
  w.w = (unsigned)f2bf(v1.z) | ((unsigned)f2bf(v1.w) << 16);
  *(uint4*)(Ag + base) = w;
}

// ---------------------------------------------------------------------------
// 256x256-tile bf16 MFMA GEMM, 8 waves (512 thr), BK=64, 2-deep prefetch with
// counted vmcnt; LDS holds tiles in MFMA-fragment order (16-row x 8-k blocks
// of 256B) so every ds_read_b128 is base + lane*16 (conflict-free), with the
// inverse permutation applied to the per-lane global source address.
// EPI: 0=f32 store, 1=relu->bf16, 2=f32 +=, 3=bf16 store, 4=f32 += val+extra[b][col]
template<int EPI>
__global__ __launch_bounds__(512) void gemm_big(
    const ushort* __restrict__ A, const ushort* __restrict__ W,
    const float* __restrict__ bias, const float* __restrict__ extra,
    void* __restrict__ Cout, int M, int N, int K)
{
  __shared__ ushort lds[65536];  // A0 | B0 | A1 | B1, 32 KB each
  const int tid = threadIdx.x;
  const int lane = tid & 63, wv = tid >> 6;
  const int wr = wv >> 2, wc = wv & 3;        // 2 x 4 waves, wave tile 128x64
  const int l = lane & 15, g = lane >> 4;
  const int row0 = blockIdx.y << 8, col0 = blockIdx.x << 8;
  const int nt = K >> 6;

  f32x4 acc[8][4] = {};

  auto STAGE = [&](int t) {
    const int k0 = t << 6;
    ushort* Ab = lds + ((t & 1) << 15);
    ushort* Bb = Ab + 16384;
    #pragma unroll
    for (int j = 0; j < 4; j++) {
      int cell = j * 512 + tid;
      int blk = cell >> 4, li = cell & 15;
      int row = ((blk >> 3) << 4) + li, col = (blk & 7) << 3;
      gload16(A + (size_t)(row0 + row) * K + k0 + col, Ab + cell * 8);
    }
    #pragma unroll
    for (int j = 0; j < 4; j++) {
      int cell = j * 512 + tid;
      int blk = cell >> 4, li = cell & 15;
      int row = ((blk >> 3) << 4) + li, col = (blk & 7) << 3;
      gload16(W + (size_t)(col0 + row) * K + k0 + col, Bb + cell * 8);
    }
  };

  auto COMPUTE = [&](int t) {
    const ushort* Ab = lds + ((t & 1) << 15);
    const ushort* Bb = Ab + 16384;
    #pragma unroll
    for (int kk = 0; kk < 2; kk++) {
      bf16x8 af[8], bfr[4];
      #pragma unroll
      for (int m = 0; m < 8; m++)
        af[m] = *(const bf16x8*)(Ab + (((wr * 8 + m) * 8 + kk * 4 + g) << 7) + l * 8);
      #pragma unroll
      for (int n = 0; n < 4; n++)
        bfr[n] = *(const bf16x8*)(Bb + (((wc * 4 + n) * 8 + kk * 4 + g) << 7) + l * 8);
      __builtin_amdgcn_s_setprio(1);
      #pragma unroll
      for (int m = 0; m < 8; m++)
        #pragma unroll
        for (int n = 0; n < 4; n++)
          acc[m][n] = __builtin_amdgcn_mfma_f32_16x16x32_bf16(af[m], bfr[n], acc[m][n], 0, 0, 0);
      __builtin_amdgcn_s_setprio(0);
    }
  };

  STAGE(0);
  STAGE(1);

  for (int t = 0; t < nt - 1; t++) {
    __builtin_amdgcn_sched_barrier(0);
    asm volatile("s_waitcnt vmcnt(8)" ::: "memory");
    __builtin_amdgcn_sched_barrier(0);
    __builtin_amdgcn_s_barrier();
    __builtin_amdgcn_sched_barrier(0);
    COMPUTE(t);
    __builtin_amdgcn_sched_barrier(0);
    __builtin_amdgcn_s_barrier();
    __builtin_amdgcn_sched_barrier(0);
    if (t + 2 < nt) STAGE(t + 2);
  }
  __builtin_amdgcn_sched_barrier(0);
  asm volatile("s_waitcnt vmcnt(0)" ::: "memory");
  __builtin_amdgcn_sched_barrier(0);
  __builtin_amdgcn_s_barrier();
  __builtin_amdgcn_sched_barrier(0);
  COMPUTE(nt - 1);

  // epilogue: C row = row0 + wr*128 + m*16 + g*4 + j, col = col0 + wc*64 + n*16 + l
  #pragma unroll
  for (int m = 0; m < 8; m++) {
    const int rb = row0 + wr * 128 + m * 16 + g * 4;
    #pragma unroll
    for (int n = 0; n < 4; n++) {
      const int col = col0 + wc * 64 + n * 16 + l;
      const float bv = bias[col];
      #pragma unroll
      for (int j = 0; j < 4; j++) {
        const int grow = rb + j;
        float val = acc[m][n][j] + bv;
        size_t off = (size_t)grow * N + col;
        if (EPI == 0) ((float*)Cout)[off] = val;
        else if (EPI == 1) ((ushort*)Cout)[off] = f2bf(fmaxf(val, 0.f));
        else if (EPI == 2) ((float*)Cout)[off] += val;
        else if (EPI == 3) ((ushort*)Cout)[off] = f2bf(val);
        else if (EPI == 4) ((float*)Cout)[off] += val + extra[(grow >> 9) * 512 + col];
      }
    }
  }
}

// ---------------------------------------------------------------------------
// LayerNorm: one wave per row, bf16 output.
__global__ __launch_bounds__(256) void ln_bf(const float* __restrict__ in,
    ushort* __restrict__ out, const float* __restrict__ g, const float* __restrict__ b)
{
  int row  = (blockIdx.x << 2) + (threadIdx.x >> 6);
  int lane = threadIdx.x & 63;
  const float* r = in + (size_t)row * D_;
  float4 v0 = *(const float4*)(r + lane * 4);
  float4 v1 = *(const float4*)(r + 256 + lane * 4);
  float s = v0.x + v0.y + v0.z + v0.w + v1.x + v1.y + v1.z + v1.w;
  #pragma unroll
  for (int m = 1; m < 64; m <<= 1) s += __shfl_xor(s, m);
  float mean = s * (1.0f / 512.0f);
  float a0 = v0.x - mean, a1 = v0.y - mean, a2 = v0.z - mean, a3 = v0.w - mean;
  float a4 = v1.x - mean, a5 = v1.y - mean, a6 = v1.z - mean, a7 = v1.w - mean;
  float sq = a0*a0 + a1*a1 + a2*a2 + a3*a3 + a4*a4 + a5*a5 + a6*a6 + a7*a7;
  #pragma unroll
  for (int m = 1; m < 64; m <<= 1) sq += __shfl_xor(sq, m);
  float inv = rsqrtf(sq * (1.0f / 512.0f) + 1e-5f);
  float4 g0 = *(const float4*)(g + lane * 4);
  float4 g1 = *(const float4*)(g + 256 + lane * 4);
  float4 b0 = *(const float4*)(b + lane * 4);
  float4 b1 = *(const float4*)(b + 256 + lane * 4);
  ushort* o = out + (size_t)row * D_;
  ushort4 u0, u1;
  u0.x = f2bf(a0*inv*g0.x + b0.x); u0.y = f2bf(a1*inv*g0.y + b0.y);
  u0.z = f2bf(a2*inv*g0.z + b0.z); u0.w = f2bf(a3*inv*g0.w + b0.w);
  u1.x = f2bf(a4*inv*g1.x + b1.x); u1.y = f2bf(a5*inv*g1.y + b1.y);
  u1.z = f2bf(a6*inv*g1.z + b1.z); u1.w = f2bf(a7*inv*g1.w + b1.w);
  *(ushort4*)(o + lane * 4) = u0;
  *(ushort4*)(o + 256 + lane * 4) = u1;
}

// ---------------------------------------------------------------------------
// MFMA flash attention (unchanged from round 3; passed).
#define QS_ 88
#define PS_ 72
template<int MODE>
__global__ __launch_bounds__(256) void attn_mfma(const ushort* __restrict__ qkv,
    ushort* __restrict__ og, float* __restrict__ pout)
{
  __shared__ ushort Qs[64 * QS_];
  __shared__ ushort Ks[64 * QS_];
  __shared__ ushort Vt[64 * PS_];
  __shared__ ushort Ps[64 * PS_];
  const int qt = 7 - blockIdx.x;
  const int h = blockIdx.y, b = blockIdx.z;
  const int tid = threadIdx.x;
  const int w = tid >> 6, lane = tid & 63;
  const int l = lane & 15, g = lane >> 4;
  const size_t qbase = ((size_t)b * S_) * 1536 + h * 64;

  #pragma unroll
  for (int p = 0; p < 2; p++) {
    int c = p * 256 + tid; int r = c >> 3, col = (c & 7) * 8;
    *(bf16x8*)&Qs[r * QS_ + col] =
        *(const bf16x8*)(qkv + qbase + (size_t)(qt * 64 + r) * 1536 + col);
  }

  float mrow[4] = {-3e38f, -3e38f, -3e38f, -3e38f};
  float lrow[4] = {0.f, 0.f, 0.f, 0.f};
  f32x4 oacc[4] = {};

  if (MODE == 1) {
    for (int kt = 0; kt <= qt; kt++) {
      __syncthreads();
      #pragma unroll
      for (int p = 0; p < 2; p++) {
        int c = p * 256 + tid; int r = c >> 3, col = (c & 7) * 8;
        *(bf16x8*)&Ks[r * QS_ + col] =
            *(const bf16x8*)(qkv + qbase + 512 + (size_t)(kt * 64 + r) * 1536 + col);
      }
      __syncthreads();
      f32x4 acc[4] = {};
      #pragma unroll
      for (int kk = 0; kk < 2; kk++) {
        bf16x8 aq = *(const bf16x8*)&Qs[(w * 16 + l) * QS_ + kk * 32 + 8 * g];
        #pragma unroll
        for (int n = 0; n < 4; n++) {
          bf16x8 bk = *(const bf16x8*)&Ks[(n * 16 + l) * QS_ + kk * 32 + 8 * g];
          acc[n] = __builtin_amdgcn_mfma_f32_16x16x32_bf16(aq, bk, acc[n], 0, 0, 0);
        }
      }
      const bool diag = (kt == qt);
      #pragma unroll
      for (int j = 0; j < 4; j++) {
        int qloc = w * 16 + 4 * g + j;
        float sv[4];
        #pragma unroll
        for (int n = 0; n < 4; n++) {
          float v = acc[n][j] * 0.125f;
          if (diag && (n * 16 + l > qloc)) v = -3e38f;
          sv[n] = v;
        }
        float rm = fmaxf(fmaxf(sv[0], sv[1]), fmaxf(sv[2], sv[3]));
        #pragma unroll
        for (int mk = 1; mk < 16; mk <<= 1) rm = fmaxf(rm, __shfl_xor(rm, mk));
        float nm = fmaxf(mrow[j], rm);
        float fac = __expf(mrow[j] - nm);
        mrow[j] = nm;
        float ps = 0.f;
        #pragma unroll
        for (int n = 0; n < 4; n++) ps += __expf(sv[n] - nm);
        #pragma unroll
        for (int mk = 1; mk < 16; mk <<= 1) ps += __shfl_xor(ps, mk);
        lrow[j] = lrow[j] * fac + ps;
      }
    }
  }

  float invl[4];
  if (MODE == 1) {
    #pragma unroll
    for (int j = 0; j < 4; j++) invl[j] = 1.0f / lrow[j];
  }

  for (int kt = 0; kt <= qt; kt++) {
    __syncthreads();
    #pragma unroll
    for (int p = 0; p < 2; p++) {
      int c = p * 256 + tid; int r = c >> 3, col = (c & 7) * 8;
      *(bf16x8*)&Ks[r * QS_ + col] =
          *(const bf16x8*)(qkv + qbase + 512 + (size_t)(kt * 64 + r) * 1536 + col);
    }
    #pragma unroll
    for (int p = 0; p < 2; p++) {
      int c = p * 256 + tid; int key = c & 63, d0 = (c >> 6) * 8;
      bf16x8 vv = *(const bf16x8*)(qkv + qbase + 1024 + (size_t)(kt * 64 + key) * 1536 + d0);
      #pragma unroll
      for (int j = 0; j < 8; j++) Vt[(d0 + j) * PS_ + key] = (ushort)vv[j];
    }
    __syncthreads();

    f32x4 acc[4] = {};
    #pragma unroll
    for (int kk = 0; kk < 2; kk++) {
      bf16x8 aq = *(const bf16x8*)&Qs[(w * 16 + l) * QS_ + kk * 32 + 8 * g];
      #pragma unroll
      for (int n = 0; n < 4; n++) {
        bf16x8 bk = *(const bf16x8*)&Ks[(n * 16 + l) * QS_ + kk * 32 + 8 * g];
        acc[n] = __builtin_amdgcn_mfma_f32_16x16x32_bf16(aq, bk, acc[n], 0, 0, 0);
      }
    }
    const bool diag = (kt == qt);

    #pragma unroll
    for (int j = 0; j < 4; j++) {
      int qloc = w * 16 + 4 * g + j;
      float sv[4];
      #pragma unroll
      for (int n = 0; n < 4; n++) {
        float v = acc[n][j] * 0.125f;
        if (diag && (n * 16 + l > qloc)) v = -3e38f;
        sv[n] = v;
      }
      if (MODE == 0) {
        float rm = fmaxf(fmaxf(sv[0], sv[1]), fmaxf(sv[2], sv[3]));
        #pragma unroll
        for (int mk = 1; mk < 16; mk <<= 1) rm = fmaxf(rm, __shfl_xor(rm, mk));
        float nm = fmaxf(mrow[j], rm);
        float fac = __expf(mrow[j] - nm);
        mrow[j] = nm;
        float ps = 0.f, pv[4];
        #pragma unroll
        for (int n = 0; n < 4; n++) { pv[n] = __expf(sv[n] - nm); ps += pv[n]; }
        #pragma unroll
        for (int mk = 1; mk < 16; mk <<= 1) ps += __shfl_xor(ps, mk);
        lrow[j] = lrow[j] * fac + ps;
        #pragma unroll
        for (int n = 0; n < 4; n++) oacc[n][j] *= fac;
        #pragma unroll
        for (int n = 0; n < 4; n++)
          Ps[(w * 16 + 4 * g + j) * PS_ + n * 16 + l] = f2bf(pv[n]);
      } else {
        #pragma unroll
        for (int n = 0; n < 4; n++) {
          float p = __expf(sv[n] - mrow[j]) * invl[j];
          Ps[(w * 16 + 4 * g + j) * PS_ + n * 16 + l] = f2bf(p);
        }
      }
    }

    if (MODE == 1) {
      __syncthreads();
      #pragma unroll
      for (int i = 0; i < 4; i++) {
        int c = i * 256 + tid; int r = c >> 4, col = (c & 15) * 4;
        float4 o4;
        o4.x = bf2f(Ps[r * PS_ + col + 0]);
        o4.y = bf2f(Ps[r * PS_ + col + 1]);
        o4.z = bf2f(Ps[r * PS_ + col + 2]);
        o4.w = bf2f(Ps[r * PS_ + col + 3]);
        *(float4*)(pout + ((size_t)(b * H_ + h) * S_ + qt * 64 + r) * S_ + kt * 64 + col) = o4;
      }
    }

    #pragma unroll
    for (int kk = 0; kk < 2; kk++) {
      bf16x8 pa = *(const bf16x8*)&Ps[(w * 16 + l) * PS_ + kk * 32 + 8 * g];
      #pragma unroll
      for (int n = 0; n < 4; n++) {
        bf16x8 vb = *(const bf16x8*)&Vt[(n * 16 + l) * PS_ + kk * 32 + 8 * g];
        oacc[n] = __builtin_amdgcn_mfma_f32_16x16x32_bf16(pa, vb, oacc[n], 0, 0, 0);
      }
    }
  }

  if (MODE == 1) {
    for (int kt = qt + 1; kt < 8; kt++) {
      #pragma unroll
      for (int i = 0; i < 4; i++) {
        int c = i * 256 + tid; int r = c >> 4, col = (c & 15) * 4;
        *(float4*)(pout + ((size_t)(b * H_ + h) * S_ + qt * 64 + r) * S_ + kt * 64 + col) =
            make_float4(0.f, 0.f, 0.f, 0.f);
      }
    }
  }

  #pragma unroll
  for (int j = 0; j < 4; j++) {
    float inv = (MODE == 0) ? 1.0f / lrow[j] : 1.0f;
    size_t rowoff = (size_t)(b * S_ + qt * 64 + w * 16 + 4 * g + j) * 512 + h * 64;
    #pragma unroll
    for (int n = 0; n < 4; n++)
      og[rowoff + n * 16 + l] = f2bf(oacc[n][j] * inv);
  }
}

// ---------------------------------------------------------------------------
__global__ __launch_bounds__(128) void embed_finish(float* __restrict__ h,
    const int* __restrict__ x, const float* __restrict__ cmd_emb,
    const float* __restrict__ cls_emb, const int* __restrict__ trg_char)
{
  int m = blockIdx.x, b = m >> 9, s = m & 511;
  int d = threadIdx.x << 2;
  float4* hp = (float4*)(h + (size_t)m * D_ + d);
  if (s == 0) {
    int c = trg_char[b];
    *hp = *(const float4*)(cls_emb + (size_t)c * D_ + d);
  } else {
    int cmd = x[(size_t)(s * B_ + b) * 9];
    float4 v  = *hp;
    float4 ce = *(const float4*)(cmd_emb + (size_t)cmd * D_ + d);
    const float kfac = -0.017988946039f;   // -ln(10000)/512
    int i0 = d >> 1;
    float ang0 = (float)s * expf((float)(2 * i0) * kfac);
    float ang1 = (float)s * expf((float)(2 * (i0 + 1)) * kfac);
    v.x += ce.x + sinf(ang0);
    v.y += ce.y + cosf(ang0);
    v.z += ce.z + sinf(ang1);
    v.w += ce.w + cosf(ang1);
    *hp = v;
  }
}

// ---------------------------------------------------------------------------
__global__ __launch_bounds__(256) void ca_stage(const float* __restrict__ in,
    const float* __restrict__ ca_w, const float* __restrict__ ca_b,
    float* __restrict__ outb, int wsel, int in_is_per_l)
{
  int l = blockIdx.x >> 5, b = blockIdx.x & 31;
  __shared__ float sm[512];
  const float* src = in_is_per_l ? in + ((size_t)l * 32 + b) * 512 : in + (size_t)b * 512;
  for (int i = threadIdx.x; i < 512; i += 256) sm[i] = src[i];
  __syncthreads();
  const float* Wl = ca_w + ((size_t)(l * 4 + wsel)) * 512 * 512;
  const float* bl = ca_b + (l * 4 + wsel) * 512;
  for (int n = threadIdx.x; n < 512; n += 256) {
    const float* wr = Wl + (size_t)n * 512;
    float acc = 0.f;
    for (int k2 = 0; k2 < 512; k2 += 4) {
      float4 w4 = *(const float4*)(wr + k2);
      acc += sm[k2] * w4.x + sm[k2+1] * w4.y + sm[k2+2] * w4.z + sm[k2+3] * w4.w;
    }
    outb[((size_t)l * 32 + b) * 512 + n] = acc + bl[n];
  }
}

__global__ __launch_bounds__(256) void cmd_head(const ushort* __restrict__ xn,
    const float* __restrict__ cw, const float* __restrict__ cb, float* __restrict__ out)
{
  int row  = (blockIdx.x << 2) + (threadIdx.x >> 6);
  int lane = threadIdx.x & 63;
  uint4 raw = *(const uint4*)(xn + (size_t)row * D_ + lane * 8);
  float x0 = bf2f(raw.x & 0xffff), x1 = bf2f(raw.x >> 16);
  float x2 = bf2f(raw.y & 0xffff), x3 = bf2f(raw.y >> 16);
  float x4 = bf2f(raw.z & 0xffff), x5 = bf2f(raw.z >> 16);
  float x6 = bf2f(raw.w & 0xffff), x7 = bf2f(raw.w >> 16);
  #pragma unroll
  for (int n = 0; n < 4; n++) {
    const float* w = cw + n * 512 + lane * 8;
    float4 w0 = *(const float4*)w, w1 = *(const float4*)(w + 4);
    float p = x0*w0.x + x1*w0.y + x2*w0.z + x3*w0.w
            + x4*w1.x + x5*w1.y + x6*w1.z + x7*w1.w;
    #pragma unroll
    for (int m = 1; m < 64; m <<= 1) p += __shfl_xor(p, m);
    if (lane == 0) out[(size_t)row * 4 + n] = p + cb[n];
  }
}

// ---------------------------------------------------------------------------
extern "C" void kernel_launch(void* const* d_in, const int* in_sizes, int n_in,
                              void* d_out, int out_size, void* d_ws, size_t ws_size,
                              hipStream_t stream)
{
  const int*   x          = (const int*)  d_in[0];
  const float* memory     = (const float*)d_in[1];
  const int*   trg_char   = (const int*)  d_in[2];
  const float* cmd_emb    = (const float*)d_in[4];
  const float* arg_emb    = (const float*)d_in[5];
  const float* embed_w    = (const float*)d_in[6];
  const float* embed_b    = (const float*)d_in[7];
  const float* sa_w       = (const float*)d_in[8];
  const float* sa_b       = (const float*)d_in[9];
  const float* ca_w       = (const float*)d_in[10];
  const float* ca_b       = (const float*)d_in[11];
  const float* ff_w1      = (const float*)d_in[12];
  const float* ff_b1      = (const float*)d_in[13];
  const float* ff_w2      = (const float*)d_in[14];
  const float* ff_b2      = (const float*)d_in[15];
  const float* ln_g       = (const float*)d_in[16];
  const float* ln_b       = (const float*)d_in[17];
  const float* fn_g       = (const float*)d_in[18];
  const float* fn_b       = (const float*)d_in[19];
  const float* cls_emb    = (const float*)d_in[20];
  const float* cmd_w      = (const float*)d_in[21];
  const float* cmd_b      = (const float*)d_in[22];
  const float* argf_w     = (const float*)d_in[23];
  const float* argf_b     = (const float*)d_in[24];

  float* out_cmd  = (float*)d_out;
  float* out_args = out_cmd + (size_t)M_ * 4;
  float* out_attn = out_args + (size_t)M_ * 1024;

  const size_t MS = (size_t)M_ * D_;     // 8388608
  float* ws = (float*)d_ws;
  float*  h      = ws;                                   // MS f32
  ushort* qkv_bf = (ushort*)(ws + MS);                   // M*1536 bf16
  ushort* xn_bf  = (ushort*)(ws + MS + 12582912);        // M*512
  ushort* o_bf   = (ushort*)(ws + MS + 16777216);        // M*512
  ushort* tA_bf  = (ushort*)(ws + MS + 20971520);        // M*1024
  ushort* wbf    = (ushort*)(ws + MS + 29360128);
  ushort* sa_wb   = wbf;                                 // 6291456
  ushort* ff1_wb  = wbf + 6291456;                       // 3145728
  ushort* ff2_wb  = wbf + 9437184;                       // 3145728
  ushort* emb_wb  = wbf + 12582912;                      // 524288
  ushort* argf_wb = wbf + 13107200;                      // 524288
  float* vvec   = ws + MS + 29360128 + 6815744;
  float* ca_out = vvec + 6 * 32 * 512;

  dim3 blk256(256), blk128(128), blk512(512);
  dim3 g_g512(2, 64);      // N=512, 256x256 tiles
  dim3 g_g1024(4, 64);     // N=1024
  dim3 g_g1536(6, 64);     // N=1536
  dim3 g_ln(M_ / 4);
  dim3 g_attn(8, H_, B_);
  dim3 g_row(M_);

  cvt_bf16<<<dim3(3072), blk256, 0, stream>>>(sa_w,   sa_wb,   786432);
  cvt_bf16<<<dim3(1536), blk256, 0, stream>>>(ff_w1,  ff1_wb,  393216);
  cvt_bf16<<<dim3(1536), blk256, 0, stream>>>(ff_w2,  ff2_wb,  393216);
  cvt_bf16<<<dim3(256),  blk256, 0, stream>>>(embed_w, emb_wb,  65536);
  cvt_bf16<<<dim3(256),  blk256, 0, stream>>>(argf_w, argf_wb,  65536);

  ca_stage<<<dim3(L_ * 32), blk256, 0, stream>>>(memory, ca_w, ca_b, vvec, 2, 0);
  ca_stage<<<dim3(L_ * 32), blk256, 0, stream>>>(vvec, ca_w, ca_b, ca_out, 3, 1);

  gather_emb<<<dim3(8192), blk256, 0, stream>>>(x, arg_emb, tA_bf);
  gemm_big<0><<<g_g512, blk512, 0, stream>>>(tA_bf, emb_wb, embed_b, nullptr, h, M_, D_, 1024);
  embed_finish<<<g_row, blk128, 0, stream>>>(h, x, cmd_emb, cls_emb, trg_char);

  for (int l = 0; l < L_; l++) {
    const ushort* saW = sa_wb + (size_t)l * 4 * D_ * D_;
    const float*  saB = sa_b + (size_t)l * 4 * D_;
    ln_bf<<<g_ln, blk256, 0, stream>>>(h, xn_bf, ln_g + (l * 3 + 0) * D_, ln_b + (l * 3 + 0) * D_);
    // fused QKV projection (w0|w1|w2 contiguous rows)
    gemm_big<3><<<g_g1536, blk512, 0, stream>>>(xn_bf, saW, saB, nullptr, qkv_bf, M_, 1536, D_);
    if (l == L_ - 1)
      attn_mfma<1><<<g_attn, blk256, 0, stream>>>(qkv_bf, o_bf, out_attn);
    else
      attn_mfma<0><<<g_attn, blk256, 0, stream>>>(qkv_bf, o_bf, nullptr);
    // output projection + residual + cross-attn broadcast (fused)
    gemm_big<4><<<g_g512, blk512, 0, stream>>>(o_bf, saW + (size_t)3*D_*D_, saB + 3*D_,
                                               ca_out + (size_t)l * 32 * D_, h, M_, D_, D_);
    ln_bf<<<g_ln, blk256, 0, stream>>>(h, xn_bf, ln_g + (l * 3 + 2) * D_, ln_b + (l * 3 + 2) * D_);
    gemm_big<1><<<g_g1024, blk512, 0, stream>>>(xn_bf, ff1_wb + (size_t)l*DFF_*D_, ff_b1 + l*DFF_, nullptr, tA_bf, M_, DFF_, D_);
    gemm_big<2><<<g_g512,  blk512, 0, stream>>>(tA_bf, ff2_wb + (size_t)l*D_*DFF_, ff_b2 + l*D_, nullptr, h, M_, D_, DFF_);
  }

  ln_bf<<<g_ln, blk256, 0, stream>>>(h, xn_bf, fn_g, fn_b);
  gemm_big<0><<<g_g1024, blk512, 0, stream>>>(xn_bf, argf_wb, argf_b, nullptr, out_args, M_, 1024, D_);
  cmd_head<<<dim3(M_ / 4), blk256, 0, stream>>>(xn_bf, cmd_w, cmd_b, out_cmd);
}

// Round 5
// 1688.387 us; speedup vs baseline: 1.1885x; 1.1885x over previous
//
#include <hip/hip_runtime.h>
#include <hip/hip_bf16.h>

#define S_ 512
#define B_ 32
#define D_ 512
#define H_ 8
#define L_ 6
#define DFF_ 1024
#define M_ (B_*S_)   // 16384 rows

typedef __attribute__((ext_vector_type(8))) short bf16x8;
typedef __attribute__((ext_vector_type(4))) float f32x4;

__device__ __forceinline__ ushort f2bf(float f) {
  union { float f; unsigned int u; } x; x.f = f;
  unsigned int r = x.u + 0x7fffu + ((x.u >> 16) & 1u);
  return (ushort)(r >> 16);
}
__device__ __forceinline__ float bf2f(unsigned int u) {
  union { unsigned int u; float f; } x; x.u = u << 16;
  return x.f;
}

__device__ __forceinline__ void gload16(const ushort* g, ushort* l) {
  __builtin_amdgcn_global_load_lds(
      (const __attribute__((address_space(1))) unsigned int*)g,
      (__attribute__((address_space(3))) unsigned int*)l, 16, 0, 0);
}

// ---------------------------------------------------------------------------
// f32 -> bf16 bulk convert
__global__ __launch_bounds__(256) void cvt_bf16(const float* __restrict__ in,
    ushort* __restrict__ out, int n8)
{
  int t = blockIdx.x * 256 + threadIdx.x;
  if (t >= n8) return;
  const float4* p = (const float4*)(in + (size_t)t * 8);
  float4 v0 = p[0], v1 = p[1];
  uint4 w;
  w.x = (unsigned)f2bf(v0.x) | ((unsigned)f2bf(v0.y) << 16);
  w.y = (unsigned)f2bf(v0.z) | ((unsigned)f2bf(v0.w) << 16);
  w.z = (unsigned)f2bf(v1.x) | ((unsigned)f2bf(v1.y) << 16);
  w.w = (unsigned)f2bf(v1.z) | ((unsigned)f2bf(v1.w) << 16);
  *(uint4*)(out + (size_t)t * 8) = w;
}

// ---------------------------------------------------------------------------
// Gather embedding rows into bf16 A matrix [16384][1024]
__global__ __launch_bounds__(256) void gather_emb(const int* __restrict__ x,
    const float* __restrict__ arg_emb, ushort* __restrict__ Ag)
{
  int t = blockIdx.x * 256 + threadIdx.x;
  size_t base = (size_t)t * 8;
  int m = (int)(base >> 10), kk = (int)(base & 1023);
  int j = kk >> 7, c = kk & 127;
  int b = m >> 9, s = m & 511;
  int a = x[(size_t)(s * B_ + b) * 9 + 1 + j];
  const float4* p = (const float4*)(arg_emb + (size_t)a * 128 + c);
  float4 v0 = p[0], v1 = p[1];
  uint4 w;
  w.x = (unsigned)f2bf(v0.x) | ((unsigned)f2bf(v0.y) << 16);
  w.y = (unsigned)f2bf(v0.z) | ((unsigned)f2bf(v0.w) << 16);
  w.z = (unsigned)f2bf(v1.x) | ((unsigned)f2bf(v1.y) << 16);
  w.w = (unsigned)f2bf(v1.z) | ((unsigned)f2bf(v1.w) << 16);
  *(uint4*)(Ag + base) = w;
}

// ---------------------------------------------------------------------------
// bf16 MFMA GEMM (128x128 tile, 4 waves, proven structure):
// C[M,N] = epi(A[M,K] @ W[N,K]^T + bias)
// EPI: 0=f32 store, 1=relu->bf16, 2=f32 +=, 3=bf16 store,
//      4=f32 += val + extra[row>>9][col]  (residual + per-batch broadcast)
template<int EPI>
__global__ __launch_bounds__(256) void gemm_mfma(
    const ushort* __restrict__ A, const ushort* __restrict__ W,
    const float* __restrict__ bias, const float* __restrict__ extra,
    void* __restrict__ Cout, int M, int N, int K)
{
  __shared__ ushort As[128 * 64];
  __shared__ ushort Bs[128 * 64];
  const int tid = threadIdx.x;
  const int lane = tid & 63, wv = tid >> 6;
  const int wr = wv >> 1, wc = wv & 1;
  const int row0 = blockIdx.y << 7, col0 = blockIdx.x << 7;

  f32x4 acc[4][4] = {};

  for (int k0 = 0; k0 < K; k0 += 64) {
    #pragma unroll
    for (int i = 0; i < 4; i++) {
      int c = i * 256 + wv * 64 + lane;
      int r = c >> 3, c8 = (c & 7) << 3;
      gload16(A + (size_t)(row0 + r) * K + k0 + c8, As + c * 8);
      gload16(W + (size_t)(col0 + r) * K + k0 + c8, Bs + c * 8);
    }
    __syncthreads();
    #pragma unroll
    for (int kk = 0; kk < 2; kk++) {
      const int kb = kk * 32 + ((lane >> 4) << 3);
      bf16x8 af[4], bfr[4];
      #pragma unroll
      for (int m = 0; m < 4; m++)
        af[m] = *(const bf16x8*)(As + (wr * 64 + m * 16 + (lane & 15)) * 64 + kb);
      #pragma unroll
      for (int n = 0; n < 4; n++)
        bfr[n] = *(const bf16x8*)(Bs + (wc * 64 + n * 16 + (lane & 15)) * 64 + kb);
      #pragma unroll
      for (int m = 0; m < 4; m++)
        #pragma unroll
        for (int n = 0; n < 4; n++)
          acc[m][n] = __builtin_amdgcn_mfma_f32_16x16x32_bf16(af[m], bfr[n], acc[m][n], 0, 0, 0);
    }
    __syncthreads();
  }

  const int crow = row0 + wr * 64 + ((lane >> 4) << 2);
  const int ccol = col0 + wc * 64 + (lane & 15);
  #pragma unroll
  for (int n = 0; n < 4; n++) {
    int col = ccol + n * 16;
    float bv = bias[col];
    #pragma unroll
    for (int m = 0; m < 4; m++) {
      int rowb = crow + m * 16;
      #pragma unroll
      for (int j = 0; j < 4; j++) {
        const int grow = rowb + j;
        float val = acc[m][n][j] + bv;
        size_t off = (size_t)grow * N + col;
        if (EPI == 0) ((float*)Cout)[off] = val;
        else if (EPI == 1) ((ushort*)Cout)[off] = f2bf(fmaxf(val, 0.f));
        else if (EPI == 2) ((float*)Cout)[off] += val;
        else if (EPI == 3) ((ushort*)Cout)[off] = f2bf(val);
        else if (EPI == 4) ((float*)Cout)[off] += val + extra[(grow >> 9) * 512 + col];
      }
    }
  }
}

// ---------------------------------------------------------------------------
// LayerNorm: one wave per row, bf16 output.
__global__ __launch_bounds__(256) void ln_bf(const float* __restrict__ in,
    ushort* __restrict__ out, const float* __restrict__ g, const float* __restrict__ b)
{
  int row  = (blockIdx.x << 2) + (threadIdx.x >> 6);
  int lane = threadIdx.x & 63;
  const float* r = in + (size_t)row * D_;
  float4 v0 = *(const float4*)(r + lane * 4);
  float4 v1 = *(const float4*)(r + 256 + lane * 4);
  float s = v0.x + v0.y + v0.z + v0.w + v1.x + v1.y + v1.z + v1.w;
  #pragma unroll
  for (int m = 1; m < 64; m <<= 1) s += __shfl_xor(s, m);
  float mean = s * (1.0f / 512.0f);
  float a0 = v0.x - mean, a1 = v0.y - mean, a2 = v0.z - mean, a3 = v0.w - mean;
  float a4 = v1.x - mean, a5 = v1.y - mean, a6 = v1.z - mean, a7 = v1.w - mean;
  float sq = a0*a0 + a1*a1 + a2*a2 + a3*a3 + a4*a4 + a5*a5 + a6*a6 + a7*a7;
  #pragma unroll
  for (int m = 1; m < 64; m <<= 1) sq += __shfl_xor(sq, m);
  float inv = rsqrtf(sq * (1.0f / 512.0f) + 1e-5f);
  float4 g0 = *(const float4*)(g + lane * 4);
  float4 g1 = *(const float4*)(g + 256 + lane * 4);
  float4 b0 = *(const float4*)(b + lane * 4);
  float4 b1 = *(const float4*)(b + 256 + lane * 4);
  ushort* o = out + (size_t)row * D_;
  ushort4 u0, u1;
  u0.x = f2bf(a0*inv*g0.x + b0.x); u0.y = f2bf(a1*inv*g0.y + b0.y);
  u0.z = f2bf(a2*inv*g0.z + b0.z); u0.w = f2bf(a3*inv*g0.w + b0.w);
  u1.x = f2bf(a4*inv*g1.x + b1.x); u1.y = f2bf(a5*inv*g1.y + b1.y);
  u1.z = f2bf(a6*inv*g1.z + b1.z); u1.w = f2bf(a7*inv*g1.w + b1.w);
  *(ushort4*)(o + lane * 4) = u0;
  *(ushort4*)(o + 256 + lane * 4) = u1;
}

// ---------------------------------------------------------------------------
// MFMA flash attention, QBLK=128 (8 waves), KBLK=64.
// qkv: bf16 [M][1536] (q|k|v). og: bf16 [M][512].
// MODE 1: two-pass; writes normalized p (f32) incl. zeros above diagonal.
// Causal mask via global indices (q-tile spans two diagonal k-tiles).
#define QS_ 88   // Q/K LDS stride (bf16)
#define PS_ 72   // P / Vt LDS stride (bf16)
template<int MODE>
__global__ __launch_bounds__(512) void attn_mfma(const ushort* __restrict__ qkv,
    ushort* __restrict__ og, float* __restrict__ pout)
{
  __shared__ ushort Qs[128 * QS_];
  __shared__ ushort Ks[64 * QS_];
  __shared__ ushort Vt[64 * PS_];   // [d][key]
  __shared__ ushort Ps[128 * PS_];  // [q][key], per-wave 16-row regions
  const int qt = 3 - blockIdx.x;    // heavy tiles first
  const int h = blockIdx.y, b = blockIdx.z;
  const int tid = threadIdx.x;
  const int w = tid >> 6, lane = tid & 63;
  const int l = lane & 15, g = lane >> 4;
  const size_t qbase = ((size_t)b * S_) * 1536 + h * 64;
  const int q0 = qt << 7;
  const int ktmax = 2 * qt + 1;
  const int qloc = w * 16 + 4 * g;  // + j

  // stage Q (once): 128 rows x 64 cols
  #pragma unroll
  for (int p = 0; p < 2; p++) {
    int c = p * 512 + tid; int r = c >> 3, col = (c & 7) * 8;
    *(bf16x8*)&Qs[r * QS_ + col] =
        *(const bf16x8*)(qkv + qbase + (size_t)(q0 + r) * 1536 + col);
  }

  float mrow[4] = {-3e38f, -3e38f, -3e38f, -3e38f};
  float lrow[4] = {0.f, 0.f, 0.f, 0.f};
  f32x4 oacc[4] = {};

  if (MODE == 1) {
    // pass 1: m,l only
    for (int kt = 0; kt <= ktmax; kt++) {
      __syncthreads();
      {
        int c = tid; int r = c >> 3, col = (c & 7) * 8;
        *(bf16x8*)&Ks[r * QS_ + col] =
            *(const bf16x8*)(qkv + qbase + 512 + (size_t)((kt << 6) + r) * 1536 + col);
      }
      __syncthreads();
      f32x4 acc[4] = {};
      #pragma unroll
      for (int kk = 0; kk < 2; kk++) {
        bf16x8 aq = *(const bf16x8*)&Qs[(w * 16 + l) * QS_ + kk * 32 + 8 * g];
        #pragma unroll
        for (int n = 0; n < 4; n++) {
          bf16x8 bk = *(const bf16x8*)&Ks[(n * 16 + l) * QS_ + kk * 32 + 8 * g];
          acc[n] = __builtin_amdgcn_mfma_f32_16x16x32_bf16(aq, bk, acc[n], 0, 0, 0);
        }
      }
      #pragma unroll
      for (int j = 0; j < 4; j++) {
        int qg = q0 + qloc + j;
        float sv[4];
        #pragma unroll
        for (int n = 0; n < 4; n++) {
          float v = acc[n][j] * 0.125f;
          if ((kt << 6) + n * 16 + l > qg) v = -3e38f;
          sv[n] = v;
        }
        float rm = fmaxf(fmaxf(sv[0], sv[1]), fmaxf(sv[2], sv[3]));
        #pragma unroll
        for (int mk = 1; mk < 16; mk <<= 1) rm = fmaxf(rm, __shfl_xor(rm, mk));
        float nm = fmaxf(mrow[j], rm);
        float fac = __expf(mrow[j] - nm);
        mrow[j] = nm;
        float ps = 0.f;
        #pragma unroll
        for (int n = 0; n < 4; n++) ps += __expf(sv[n] - nm);
        #pragma unroll
        for (int mk = 1; mk < 16; mk <<= 1) ps += __shfl_xor(ps, mk);
        lrow[j] = lrow[j] * fac + ps;
      }
    }
  }

  float invl[4];
  if (MODE == 1) {
    #pragma unroll
    for (int j = 0; j < 4; j++) invl[j] = 1.0f / lrow[j];
  }

  // main loop
  for (int kt = 0; kt <= ktmax; kt++) {
    __syncthreads();
    {
      int c = tid; int r = c >> 3, col = (c & 7) * 8;
      *(bf16x8*)&Ks[r * QS_ + col] =
          *(const bf16x8*)(qkv + qbase + 512 + (size_t)((kt << 6) + r) * 1536 + col);
    }
    {
      int c = tid; int key = c & 63, d0 = (c >> 6) * 8;
      bf16x8 vv = *(const bf16x8*)(qkv + qbase + 1024 + (size_t)((kt << 6) + key) * 1536 + d0);
      #pragma unroll
      for (int j = 0; j < 8; j++) Vt[(d0 + j) * PS_ + key] = (ushort)vv[j];
    }
    __syncthreads();

    f32x4 acc[4] = {};
    #pragma unroll
    for (int kk = 0; kk < 2; kk++) {
      bf16x8 aq = *(const bf16x8*)&Qs[(w * 16 + l) * QS_ + kk * 32 + 8 * g];
      #pragma unroll
      for (int n = 0; n < 4; n++) {
        bf16x8 bk = *(const bf16x8*)&Ks[(n * 16 + l) * QS_ + kk * 32 + 8 * g];
        acc[n] = __builtin_amdgcn_mfma_f32_16x16x32_bf16(aq, bk, acc[n], 0, 0, 0);
      }
    }

    #pragma unroll
    for (int j = 0; j < 4; j++) {
      int qg = q0 + qloc + j;
      float sv[4];
      #pragma unroll
      for (int n = 0; n < 4; n++) {
        float v = acc[n][j] * 0.125f;
        if ((kt << 6) + n * 16 + l > qg) v = -3e38f;
        sv[n] = v;
      }
      if (MODE == 0) {
        float rm = fmaxf(fmaxf(sv[0], sv[1]), fmaxf(sv[2], sv[3]));
        #pragma unroll
        for (int mk = 1; mk < 16; mk <<= 1) rm = fmaxf(rm, __shfl_xor(rm, mk));
        float nm = fmaxf(mrow[j], rm);
        float fac = __expf(mrow[j] - nm);
        mrow[j] = nm;
        float ps = 0.f, pv[4];
        #pragma unroll
        for (int n = 0; n < 4; n++) { pv[n] = __expf(sv[n] - nm); ps += pv[n]; }
        #pragma unroll
        for (int mk = 1; mk < 16; mk <<= 1) ps += __shfl_xor(ps, mk);
        lrow[j] = lrow[j] * fac + ps;
        #pragma unroll
        for (int n = 0; n < 4; n++) oacc[n][j] *= fac;
        #pragma unroll
        for (int n = 0; n < 4; n++)
          Ps[(qloc + j) * PS_ + n * 16 + l] = f2bf(pv[n]);
      } else {
        #pragma unroll
        for (int n = 0; n < 4; n++) {
          float p = __expf(sv[n] - mrow[j]) * invl[j];
          Ps[(qloc + j) * PS_ + n * 16 + l] = f2bf(p);
        }
      }
    }

    if (MODE == 1) {
      __syncthreads();
      #pragma unroll
      for (int i = 0; i < 4; i++) {
        int c = i * 512 + tid; int r = c >> 4, col = (c & 15) * 4;
        float4 o4;
        o4.x = bf2f(Ps[r * PS_ + col + 0]);
        o4.y = bf2f(Ps[r * PS_ + col + 1]);
        o4.z = bf2f(Ps[r * PS_ + col + 2]);
        o4.w = bf2f(Ps[r * PS_ + col + 3]);
        *(float4*)(pout + ((size_t)(b * H_ + h) * S_ + q0 + r) * S_ + (kt << 6) + col) = o4;
      }
    }

    // PV: O += P @ V  (A = own-wave Ps rows, B = Vt [d][key])
    #pragma unroll
    for (int kk = 0; kk < 2; kk++) {
      bf16x8 pa = *(const bf16x8*)&Ps[(w * 16 + l) * PS_ + kk * 32 + 8 * g];
      #pragma unroll
      for (int n = 0; n < 4; n++) {
        bf16x8 vb = *(const bf16x8*)&Vt[(n * 16 + l) * PS_ + kk * 32 + 8 * g];
        oacc[n] = __builtin_amdgcn_mfma_f32_16x16x32_bf16(pa, vb, oacc[n], 0, 0, 0);
      }
    }
  }

  if (MODE == 1) {
    // zero tiles above the diagonal
    for (int kt = ktmax + 1; kt < 8; kt++) {
      #pragma unroll
      for (int i = 0; i < 4; i++) {
        int c = i * 512 + tid; int r = c >> 4, col = (c & 15) * 4;
        *(float4*)(pout + ((size_t)(b * H_ + h) * S_ + q0 + r) * S_ + (kt << 6) + col) =
            make_float4(0.f, 0.f, 0.f, 0.f);
      }
    }
  }

  // write O (bf16)
  #pragma unroll
  for (int j = 0; j < 4; j++) {
    float inv = (MODE == 0) ? 1.0f / lrow[j] : 1.0f;
    size_t rowoff = (size_t)(b * S_ + q0 + qloc + j) * 512 + h * 64;
    #pragma unroll
    for (int n = 0; n < 4; n++)
      og[rowoff + n * 16 + l] = f2bf(oacc[n][j] * inv);
  }
}

// ---------------------------------------------------------------------------
__global__ __launch_bounds__(128) void embed_finish(float* __restrict__ h,
    const int* __restrict__ x, const float* __restrict__ cmd_emb,
    const float* __restrict__ cls_emb, const int* __restrict__ trg_char)
{
  int m = blockIdx.x, b = m >> 9, s = m & 511;
  int d = threadIdx.x << 2;
  float4* hp = (float4*)(h + (size_t)m * D_ + d);
  if (s == 0) {
    int c = trg_char[b];
    *hp = *(const float4*)(cls_emb + (size_t)c * D_ + d);
  } else {
    int cmd = x[(size_t)(s * B_ + b) * 9];
    float4 v  = *hp;
    float4 ce = *(const float4*)(cmd_emb + (size_t)cmd * D_ + d);
    const float kfac = -0.017988946039f;   // -ln(10000)/512
    int i0 = d >> 1;
    float ang0 = (float)s * expf((float)(2 * i0) * kfac);
    float ang1 = (float)s * expf((float)(2 * (i0 + 1)) * kfac);
    v.x += ce.x + sinf(ang0);
    v.y += ce.y + cosf(ang0);
    v.z += ce.z + sinf(ang1);
    v.w += ce.w + cosf(ang1);
    *hp = v;
  }
}

// ---------------------------------------------------------------------------
__global__ __launch_bounds__(256) void ca_stage(const float* __restrict__ in,
    const float* __restrict__ ca_w, const float* __restrict__ ca_b,
    float* __restrict__ outb, int wsel, int in_is_per_l)
{
  int l = blockIdx.x >> 5, b = blockIdx.x & 31;
  __shared__ float sm[512];
  const float* src = in_is_per_l ? in + ((size_t)l * 32 + b) * 512 : in + (size_t)b * 512;
  for (int i = threadIdx.x; i < 512; i += 256) sm[i] = src[i];
  __syncthreads();
  const float* Wl = ca_w + ((size_t)(l * 4 + wsel)) * 512 * 512;
  const float* bl = ca_b + (l * 4 + wsel) * 512;
  for (int n = threadIdx.x; n < 512; n += 256) {
    const float* wr = Wl + (size_t)n * 512;
    float acc = 0.f;
    for (int k2 = 0; k2 < 512; k2 += 4) {
      float4 w4 = *(const float4*)(wr + k2);
      acc += sm[k2] * w4.x + sm[k2+1] * w4.y + sm[k2+2] * w4.z + sm[k2+3] * w4.w;
    }
    outb[((size_t)l * 32 + b) * 512 + n] = acc + bl[n];
  }
}

__global__ __launch_bounds__(256) void cmd_head(const ushort* __restrict__ xn,
    const float* __restrict__ cw, const float* __restrict__ cb, float* __restrict__ out)
{
  int row  = (blockIdx.x << 2) + (threadIdx.x >> 6);
  int lane = threadIdx.x & 63;
  uint4 raw = *(const uint4*)(xn + (size_t)row * D_ + lane * 8);
  float x0 = bf2f(raw.x & 0xffff), x1 = bf2f(raw.x >> 16);
  float x2 = bf2f(raw.y & 0xffff), x3 = bf2f(raw.y >> 16);
  float x4 = bf2f(raw.z & 0xffff), x5 = bf2f(raw.z >> 16);
  float x6 = bf2f(raw.w & 0xffff), x7 = bf2f(raw.w >> 16);
  #pragma unroll
  for (int n = 0; n < 4; n++) {
    const float* w = cw + n * 512 + lane * 8;
    float4 w0 = *(const float4*)w, w1 = *(const float4*)(w + 4);
    float p = x0*w0.x + x1*w0.y + x2*w0.z + x3*w0.w
            + x4*w1.x + x5*w1.y + x6*w1.z + x7*w1.w;
    #pragma unroll
    for (int m = 1; m < 64; m <<= 1) p += __shfl_xor(p, m);
    if (lane == 0) out[(size_t)row * 4 + n] = p + cb[n];
  }
}

// ---------------------------------------------------------------------------
extern "C" void kernel_launch(void* const* d_in, const int* in_sizes, int n_in,
                              void* d_out, int out_size, void* d_ws, size_t ws_size,
                              hipStream_t stream)
{
  const int*   x          = (const int*)  d_in[0];
  const float* memory     = (const float*)d_in[1];
  const int*   trg_char   = (const int*)  d_in[2];
  const float* cmd_emb    = (const float*)d_in[4];
  const float* arg_emb    = (const float*)d_in[5];
  const float* embed_w    = (const float*)d_in[6];
  const float* embed_b    = (const float*)d_in[7];
  const float* sa_w       = (const float*)d_in[8];
  const float* sa_b       = (const float*)d_in[9];
  const float* ca_w       = (const float*)d_in[10];
  const float* ca_b       = (const float*)d_in[11];
  const float* ff_w1      = (const float*)d_in[12];
  const float* ff_b1      = (const float*)d_in[13];
  const float* ff_w2      = (const float*)d_in[14];
  const float* ff_b2      = (const float*)d_in[15];
  const float* ln_g       = (const float*)d_in[16];
  const float* ln_b       = (const float*)d_in[17];
  const float* fn_g       = (const float*)d_in[18];
  const float* fn_b       = (const float*)d_in[19];
  const float* cls_emb    = (const float*)d_in[20];
  const float* cmd_w      = (const float*)d_in[21];
  const float* cmd_b      = (const float*)d_in[22];
  const float* argf_w     = (const float*)d_in[23];
  const float* argf_b     = (const float*)d_in[24];

  float* out_cmd  = (float*)d_out;
  float* out_args = out_cmd + (size_t)M_ * 4;
  float* out_attn = out_args + (size_t)M_ * 1024;

  const size_t MS = (size_t)M_ * D_;     // 8388608
  float* ws = (float*)d_ws;
  float*  h      = ws;                                   // MS f32
  ushort* qkv_bf = (ushort*)(ws + MS);                   // M*1536 bf16
  ushort* xn_bf  = (ushort*)(ws + MS + 12582912);        // M*512
  ushort* o_bf   = (ushort*)(ws + MS + 16777216);        // M*512
  ushort* tA_bf  = (ushort*)(ws + MS + 20971520);        // M*1024
  ushort* wbf    = (ushort*)(ws + MS + 29360128);
  ushort* sa_wb   = wbf;                                 // 6291456
  ushort* ff1_wb  = wbf + 6291456;                       // 3145728
  ushort* ff2_wb  = wbf + 9437184;                       // 3145728
  ushort* emb_wb  = wbf + 12582912;                      // 524288
  ushort* argf_wb = wbf + 13107200;                      // 524288
  float* vvec   = ws + MS + 29360128 + 6815744;
  float* ca_out = vvec + 6 * 32 * 512;

  dim3 blk256(256), blk128(128), blk512(512);
  dim3 g_g512(4, 128);
  dim3 g_g1024(8, 128);
  dim3 g_g1536(12, 128);
  dim3 g_ln(M_ / 4);
  dim3 g_attn(4, H_, B_);
  dim3 g_row(M_);

  cvt_bf16<<<dim3(3072), blk256, 0, stream>>>(sa_w,   sa_wb,   786432);
  cvt_bf16<<<dim3(1536), blk256, 0, stream>>>(ff_w1,  ff1_wb,  393216);
  cvt_bf16<<<dim3(1536), blk256, 0, stream>>>(ff_w2,  ff2_wb,  393216);
  cvt_bf16<<<dim3(256),  blk256, 0, stream>>>(embed_w, emb_wb,  65536);
  cvt_bf16<<<dim3(256),  blk256, 0, stream>>>(argf_w, argf_wb,  65536);

  ca_stage<<<dim3(L_ * 32), blk256, 0, stream>>>(memory, ca_w, ca_b, vvec, 2, 0);
  ca_stage<<<dim3(L_ * 32), blk256, 0, stream>>>(vvec, ca_w, ca_b, ca_out, 3, 1);

  gather_emb<<<dim3(8192), blk256, 0, stream>>>(x, arg_emb, tA_bf);
  gemm_mfma<0><<<g_g512, blk256, 0, stream>>>(tA_bf, emb_wb, embed_b, nullptr, h, M_, D_, 1024);
  embed_finish<<<g_row, blk128, 0, stream>>>(h, x, cmd_emb, cls_emb, trg_char);

  for (int l = 0; l < L_; l++) {
    const ushort* saW = sa_wb + (size_t)l * 4 * D_ * D_;
    const float*  saB = sa_b + (size_t)l * 4 * D_;
    ln_bf<<<g_ln, blk256, 0, stream>>>(h, xn_bf, ln_g + (l * 3 + 0) * D_, ln_b + (l * 3 + 0) * D_);
    // fused QKV projection (w0|w1|w2 contiguous rows)
    gemm_mfma<3><<<g_g1536, blk256, 0, stream>>>(xn_bf, saW, saB, nullptr, qkv_bf, M_, 1536, D_);
    if (l == L_ - 1)
      attn_mfma<1><<<g_attn, blk512, 0, stream>>>(qkv_bf, o_bf, out_attn);
    else
      attn_mfma<0><<<g_attn, blk512, 0, stream>>>(qkv_bf, o_bf, nullptr);
    // output projection + residual + cross-attn broadcast (fused)
    gemm_mfma<4><<<g_g512, blk256, 0, stream>>>(o_bf, saW + (size_t)3*D_*D_, saB + 3*D_,
                                                ca_out + (size_t)l * 32 * D_, h, M_, D_, D_);
    ln_bf<<<g_ln, blk256, 0, stream>>>(h, xn_bf, ln_g + (l * 3 + 2) * D_, ln_b + (l * 3 + 2) * D_);
    gemm_mfma<1><<<g_g1024, blk256, 0, stream>>>(xn_bf, ff1_wb + (size_t)l*DFF_*D_, ff_b1 + l*DFF_, nullptr, tA_bf, M_, DFF_, D_);
    gemm_mfma<2><<<g_g512,  blk256, 0, stream>>>(tA_bf, ff2_wb + (size_t)l*D_*DFF_, ff_b2 + l*D_, nullptr, h, M_, D_, DFF_);
  }

  ln_bf<<<g_ln, blk256, 0, stream>>>(h, xn_bf, fn_g, fn_b);
  gemm_mfma<0><<<g_g1024, blk256, 0, stream>>>(xn_bf, argf_wb, argf_b, nullptr, out_args, M_, 1024, D_);
  cmd_head<<<dim3(M_ / 4), blk256, 0, stream>>>(xn_bf, cmd_w, cmd_b, out_cmd);
}

// Round 8
// 1632.823 us; speedup vs baseline: 1.2289x; 1.0340x over previous
//
#include <hip/hip_runtime.h>
#include <hip/hip_bf16.h>

#define S_ 512
#define B_ 32
#define D_ 512
#define H_ 8
#define L_ 6
#define DFF_ 1024
#define M_ (B_*S_)   // 16384 rows

typedef __attribute__((ext_vector_type(8))) short bf16x8;
typedef __attribute__((ext_vector_type(4))) float f32x4;

__device__ __forceinline__ ushort f2bf(float f) {
  union { float f; unsigned int u; } x; x.f = f;
  unsigned int r = x.u + 0x7fffu + ((x.u >> 16) & 1u);
  return (ushort)(r >> 16);
}
__device__ __forceinline__ float bf2f(unsigned int u) {
  union { unsigned int u; float f; } x; x.u = u << 16;
  return x.f;
}

__device__ __forceinline__ void gload16(const ushort* g, ushort* l) {
  __builtin_amdgcn_global_load_lds(
      (const __attribute__((address_space(1))) unsigned int*)g,
      (__attribute__((address_space(3))) unsigned int*)l, 16, 0, 0);
}

// ---------------------------------------------------------------------------
// f32 -> bf16 bulk convert  (R5 form — the fused cvt_all was a R6 suspect)
__global__ __launch_bounds__(256) void cvt_bf16(const float* __restrict__ in,
    ushort* __restrict__ out, int n8)
{
  int t = blockIdx.x * 256 + threadIdx.x;
  if (t >= n8) return;
  const float4* p = (const float4*)(in + (size_t)t * 8);
  float4 v0 = p[0], v1 = p[1];
  uint4 w;
  w.x = (unsigned)f2bf(v0.x) | ((unsigned)f2bf(v0.y) << 16);
  w.y = (unsigned)f2bf(v0.z) | ((unsigned)f2bf(v0.w) << 16);
  w.z = (unsigned)f2bf(v1.x) | ((unsigned)f2bf(v1.y) << 16);
  w.w = (unsigned)f2bf(v1.z) | ((unsigned)f2bf(v1.w) << 16);
  *(uint4*)(out + (size_t)t * 8) = w;
}

// ---------------------------------------------------------------------------
// Gather embedding rows into bf16 A matrix [16384][1024]
__global__ __launch_bounds__(256) void gather_emb(const int* __restrict__ x,
    const float* __restrict__ arg_emb, ushort* __restrict__ Ag)
{
  int t = blockIdx.x * 256 + threadIdx.x;
  size_t base = (size_t)t * 8;
  int m = (int)(base >> 10), kk = (int)(base & 1023);
  int j = kk >> 7, c = kk & 127;
  int b = m >> 9, s = m & 511;
  int a = x[(size_t)(s * B_ + b) * 9 + 1 + j];
  const float4* p = (const float4*)(arg_emb + (size_t)a * 128 + c);
  float4 v0 = p[0], v1 = p[1];
  uint4 w;
  w.x = (unsigned)f2bf(v0.x) | ((unsigned)f2bf(v0.y) << 16);
  w.y = (unsigned)f2bf(v0.z) | ((unsigned)f2bf(v0.w) << 16);
  w.z = (unsigned)f2bf(v1.x) | ((unsigned)f2bf(v1.y) << 16);
  w.w = (unsigned)f2bf(v1.z) | ((unsigned)f2bf(v1.w) << 16);
  *(uint4*)(Ag + base) = w;
}

// ---------------------------------------------------------------------------
// bf16 MFMA GEMM (128x128 tile, 4 waves — the R3/R5-proven structure),
// + XCD-chunked block swizzle (bijective: all grids are multiples of 8).
// EPI: 0=f32 store, 1=relu->bf16, 2=f32 +=, 3=bf16 store,
//      4=f32 += val + extra[row>>9][col]  (residual + per-batch broadcast)
template<int EPI>
__global__ __launch_bounds__(256) void gemm_mfma(
    const ushort* __restrict__ A, const ushort* __restrict__ W,
    const float* __restrict__ bias, const float* __restrict__ extra,
    void* __restrict__ Cout, int M, int N, int K)
{
  __shared__ ushort As[128 * 64];
  __shared__ ushort Bs[128 * 64];
  const int tid = threadIdx.x;
  const int lane = tid & 63, wv = tid >> 6;
  const int wr = wv >> 1, wc = wv & 1;

  // T1: XCD-chunked swizzle. nwg % 8 == 0 for every launch config used here,
  // so (bid&7)*chunk + bid>>3 is a bijection. Consecutive swizzled ids (which
  // share A row-panels) land on the same XCD's L2.
  const int nbx = gridDim.x;
  const int bid = blockIdx.y * nbx + blockIdx.x;
  const int cpx = (nbx * gridDim.y) >> 3;
  const int swz = (bid & 7) * cpx + (bid >> 3);
  const int bx = swz % nbx, by = swz / nbx;
  const int row0 = by << 7, col0 = bx << 7;

  f32x4 acc[4][4] = {};

  for (int k0 = 0; k0 < K; k0 += 64) {
    #pragma unroll
    for (int i = 0; i < 4; i++) {
      int c = i * 256 + wv * 64 + lane;
      int r = c >> 3, c8 = (c & 7) << 3;
      gload16(A + (size_t)(row0 + r) * K + k0 + c8, As + c * 8);
      gload16(W + (size_t)(col0 + r) * K + k0 + c8, Bs + c * 8);
    }
    __syncthreads();
    #pragma unroll
    for (int kk = 0; kk < 2; kk++) {
      const int kb = kk * 32 + ((lane >> 4) << 3);
      bf16x8 af[4], bfr[4];
      #pragma unroll
      for (int m = 0; m < 4; m++)
        af[m] = *(const bf16x8*)(As + (wr * 64 + m * 16 + (lane & 15)) * 64 + kb);
      #pragma unroll
      for (int n = 0; n < 4; n++)
        bfr[n] = *(const bf16x8*)(Bs + (wc * 64 + n * 16 + (lane & 15)) * 64 + kb);
      #pragma unroll
      for (int m = 0; m < 4; m++)
        #pragma unroll
        for (int n = 0; n < 4; n++)
          acc[m][n] = __builtin_amdgcn_mfma_f32_16x16x32_bf16(af[m], bfr[n], acc[m][n], 0, 0, 0);
    }
    __syncthreads();
  }

  const int crow = row0 + wr * 64 + ((lane >> 4) << 2);
  const int ccol = col0 + wc * 64 + (lane & 15);
  #pragma unroll
  for (int n = 0; n < 4; n++) {
    int col = ccol + n * 16;
    float bv = bias[col];
    #pragma unroll
    for (int m = 0; m < 4; m++) {
      int rowb = crow + m * 16;
      #pragma unroll
      for (int j = 0; j < 4; j++) {
        const int grow = rowb + j;
        float val = acc[m][n][j] + bv;
        size_t off = (size_t)grow * N + col;
        if (EPI == 0) ((float*)Cout)[off] = val;
        else if (EPI == 1) ((ushort*)Cout)[off] = f2bf(fmaxf(val, 0.f));
        else if (EPI == 2) ((float*)Cout)[off] += val;
        else if (EPI == 3) ((ushort*)Cout)[off] = f2bf(val);
        else if (EPI == 4) ((float*)Cout)[off] += val + extra[(grow >> 9) * 512 + col];
      }
    }
  }
}

// ---------------------------------------------------------------------------
// LayerNorm: one wave per row, bf16 output.
__global__ __launch_bounds__(256) void ln_bf(const float* __restrict__ in,
    ushort* __restrict__ out, const float* __restrict__ g, const float* __restrict__ b)
{
  int row  = (blockIdx.x << 2) + (threadIdx.x >> 6);
  int lane = threadIdx.x & 63;
  const float* r = in + (size_t)row * D_;
  float4 v0 = *(const float4*)(r + lane * 4);
  float4 v1 = *(const float4*)(r + 256 + lane * 4);
  float s = v0.x + v0.y + v0.z + v0.w + v1.x + v1.y + v1.z + v1.w;
  #pragma unroll
  for (int m = 1; m < 64; m <<= 1) s += __shfl_xor(s, m);
  float mean = s * (1.0f / 512.0f);
  float a0 = v0.x - mean, a1 = v0.y - mean, a2 = v0.z - mean, a3 = v0.w - mean;
  float a4 = v1.x - mean, a5 = v1.y - mean, a6 = v1.z - mean, a7 = v1.w - mean;
  float sq = a0*a0 + a1*a1 + a2*a2 + a3*a3 + a4*a4 + a5*a5 + a6*a6 + a7*a7;
  #pragma unroll
  for (int m = 1; m < 64; m <<= 1) sq += __shfl_xor(sq, m);
  float inv = rsqrtf(sq * (1.0f / 512.0f) + 1e-5f);
  float4 g0 = *(const float4*)(g + lane * 4);
  float4 g1 = *(const float4*)(g + 256 + lane * 4);
  float4 b0 = *(const float4*)(b + lane * 4);
  float4 b1 = *(const float4*)(b + 256 + lane * 4);
  ushort* o = out + (size_t)row * D_;
  ushort4 u0, u1;
  u0.x = f2bf(a0*inv*g0.x + b0.x); u0.y = f2bf(a1*inv*g0.y + b0.y);
  u0.z = f2bf(a2*inv*g0.z + b0.z); u0.w = f2bf(a3*inv*g0.w + b0.w);
  u1.x = f2bf(a4*inv*g1.x + b1.x); u1.y = f2bf(a5*inv*g1.y + b1.y);
  u1.z = f2bf(a6*inv*g1.z + b1.z); u1.w = f2bf(a7*inv*g1.w + b1.w);
  *(ushort4*)(o + lane * 4) = u0;
  *(ushort4*)(o + 256 + lane * 4) = u1;
}

// ---------------------------------------------------------------------------
// MFMA flash attention, QBLK=128 (8 waves), KBLK=64.  (R5-proven, unchanged)
#define QS_ 88
#define PS_ 72
template<int MODE>
__global__ __launch_bounds__(512) void attn_mfma(const ushort* __restrict__ qkv,
    ushort* __restrict__ og, float* __restrict__ pout)
{
  __shared__ ushort Qs[128 * QS_];
  __shared__ ushort Ks[64 * QS_];
  __shared__ ushort Vt[64 * PS_];
  __shared__ ushort Ps[128 * PS_];
  const int qt = 3 - blockIdx.x;
  const int h = blockIdx.y, b = blockIdx.z;
  const int tid = threadIdx.x;
  const int w = tid >> 6, lane = tid & 63;
  const int l = lane & 15, g = lane >> 4;
  const size_t qbase = ((size_t)b * S_) * 1536 + h * 64;
  const int q0 = qt << 7;
  const int ktmax = 2 * qt + 1;
  const int qloc = w * 16 + 4 * g;

  #pragma unroll
  for (int p = 0; p < 2; p++) {
    int c = p * 512 + tid; int r = c >> 3, col = (c & 7) * 8;
    *(bf16x8*)&Qs[r * QS_ + col] =
        *(const bf16x8*)(qkv + qbase + (size_t)(q0 + r) * 1536 + col);
  }

  float mrow[4] = {-3e38f, -3e38f, -3e38f, -3e38f};
  float lrow[4] = {0.f, 0.f, 0.f, 0.f};
  f32x4 oacc[4] = {};

  if (MODE == 1) {
    for (int kt = 0; kt <= ktmax; kt++) {
      __syncthreads();
      {
        int c = tid; int r = c >> 3, col = (c & 7) * 8;
        *(bf16x8*)&Ks[r * QS_ + col] =
            *(const bf16x8*)(qkv + qbase + 512 + (size_t)((kt << 6) + r) * 1536 + col);
      }
      __syncthreads();
      f32x4 acc[4] = {};
      #pragma unroll
      for (int kk = 0; kk < 2; kk++) {
        bf16x8 aq = *(const bf16x8*)&Qs[(w * 16 + l) * QS_ + kk * 32 + 8 * g];
        #pragma unroll
        for (int n = 0; n < 4; n++) {
          bf16x8 bk = *(const bf16x8*)&Ks[(n * 16 + l) * QS_ + kk * 32 + 8 * g];
          acc[n] = __builtin_amdgcn_mfma_f32_16x16x32_bf16(aq, bk, acc[n], 0, 0, 0);
        }
      }
      #pragma unroll
      for (int j = 0; j < 4; j++) {
        int qg = q0 + qloc + j;
        float sv[4];
        #pragma unroll
        for (int n = 0; n < 4; n++) {
          float v = acc[n][j] * 0.125f;
          if ((kt << 6) + n * 16 + l > qg) v = -3e38f;
          sv[n] = v;
        }
        float rm = fmaxf(fmaxf(sv[0], sv[1]), fmaxf(sv[2], sv[3]));
        #pragma unroll
        for (int mk = 1; mk < 16; mk <<= 1) rm = fmaxf(rm, __shfl_xor(rm, mk));
        float nm = fmaxf(mrow[j], rm);
        float fac = __expf(mrow[j] - nm);
        mrow[j] = nm;
        float ps = 0.f;
        #pragma unroll
        for (int n = 0; n < 4; n++) ps += __expf(sv[n] - nm);
        #pragma unroll
        for (int mk = 1; mk < 16; mk <<= 1) ps += __shfl_xor(ps, mk);
        lrow[j] = lrow[j] * fac + ps;
      }
    }
  }

  float invl[4];
  if (MODE == 1) {
    #pragma unroll
    for (int j = 0; j < 4; j++) invl[j] = 1.0f / lrow[j];
  }

  for (int kt = 0; kt <= ktmax; kt++) {
    __syncthreads();
    {
      int c = tid; int r = c >> 3, col = (c & 7) * 8;
      *(bf16x8*)&Ks[r * QS_ + col] =
          *(const bf16x8*)(qkv + qbase + 512 + (size_t)((kt << 6) + r) * 1536 + col);
    }
    {
      int c = tid; int key = c & 63, d0 = (c >> 6) * 8;
      bf16x8 vv = *(const bf16x8*)(qkv + qbase + 1024 + (size_t)((kt << 6) + key) * 1536 + d0);
      #pragma unroll
      for (int j = 0; j < 8; j++) Vt[(d0 + j) * PS_ + key] = (ushort)vv[j];
    }
    __syncthreads();

    f32x4 acc[4] = {};
    #pragma unroll
    for (int kk = 0; kk < 2; kk++) {
      bf16x8 aq = *(const bf16x8*)&Qs[(w * 16 + l) * QS_ + kk * 32 + 8 * g];
      #pragma unroll
      for (int n = 0; n < 4; n++) {
        bf16x8 bk = *(const bf16x8*)&Ks[(n * 16 + l) * QS_ + kk * 32 + 8 * g];
        acc[n] = __builtin_amdgcn_mfma_f32_16x16x32_bf16(aq, bk, acc[n], 0, 0, 0);
      }
    }

    #pragma unroll
    for (int j = 0; j < 4; j++) {
      int qg = q0 + qloc + j;
      float sv[4];
      #pragma unroll
      for (int n = 0; n < 4; n++) {
        float v = acc[n][j] * 0.125f;
        if ((kt << 6) + n * 16 + l > qg) v = -3e38f;
        sv[n] = v;
      }
      if (MODE == 0) {
        float rm = fmaxf(fmaxf(sv[0], sv[1]), fmaxf(sv[2], sv[3]));
        #pragma unroll
        for (int mk = 1; mk < 16; mk <<= 1) rm = fmaxf(rm, __shfl_xor(rm, mk));
        float nm = fmaxf(mrow[j], rm);
        float fac = __expf(mrow[j] - nm);
        mrow[j] = nm;
        float ps = 0.f, pv[4];
        #pragma unroll
        for (int n = 0; n < 4; n++) { pv[n] = __expf(sv[n] - nm); ps += pv[n]; }
        #pragma unroll
        for (int mk = 1; mk < 16; mk <<= 1) ps += __shfl_xor(ps, mk);
        lrow[j] = lrow[j] * fac + ps;
        #pragma unroll
        for (int n = 0; n < 4; n++) oacc[n][j] *= fac;
        #pragma unroll
        for (int n = 0; n < 4; n++)
          Ps[(qloc + j) * PS_ + n * 16 + l] = f2bf(pv[n]);
      } else {
        #pragma unroll
        for (int n = 0; n < 4; n++) {
          float p = __expf(sv[n] - mrow[j]) * invl[j];
          Ps[(qloc + j) * PS_ + n * 16 + l] = f2bf(p);
        }
      }
    }

    if (MODE == 1) {
      __syncthreads();
      #pragma unroll
      for (int i = 0; i < 4; i++) {
        int c = i * 512 + tid; int r = c >> 4, col = (c & 15) * 4;
        float4 o4;
        o4.x = bf2f(Ps[r * PS_ + col + 0]);
        o4.y = bf2f(Ps[r * PS_ + col + 1]);
        o4.z = bf2f(Ps[r * PS_ + col + 2]);
        o4.w = bf2f(Ps[r * PS_ + col + 3]);
        *(float4*)(pout + ((size_t)(b * H_ + h) * S_ + q0 + r) * S_ + (kt << 6) + col) = o4;
      }
    }

    #pragma unroll
    for (int kk = 0; kk < 2; kk++) {
      bf16x8 pa = *(const bf16x8*)&Ps[(w * 16 + l) * PS_ + kk * 32 + 8 * g];
      #pragma unroll
      for (int n = 0; n < 4; n++) {
        bf16x8 vb = *(const bf16x8*)&Vt[(n * 16 + l) * PS_ + kk * 32 + 8 * g];
        oacc[n] = __builtin_amdgcn_mfma_f32_16x16x32_bf16(pa, vb, oacc[n], 0, 0, 0);
      }
    }
  }

  if (MODE == 1) {
    for (int kt = ktmax + 1; kt < 8; kt++) {
      #pragma unroll
      for (int i = 0; i < 4; i++) {
        int c = i * 512 + tid; int r = c >> 4, col = (c & 15) * 4;
        *(float4*)(pout + ((size_t)(b * H_ + h) * S_ + q0 + r) * S_ + (kt << 6) + col) =
            make_float4(0.f, 0.f, 0.f, 0.f);
      }
    }
  }

  #pragma unroll
  for (int j = 0; j < 4; j++) {
    float inv = (MODE == 0) ? 1.0f / lrow[j] : 1.0f;
    size_t rowoff = (size_t)(b * S_ + q0 + qloc + j) * 512 + h * 64;
    #pragma unroll
    for (int n = 0; n < 4; n++)
      og[rowoff + n * 16 + l] = f2bf(oacc[n][j] * inv);
  }
}

// ---------------------------------------------------------------------------
__global__ __launch_bounds__(128) void embed_finish(float* __restrict__ h,
    const int* __restrict__ x, const float* __restrict__ cmd_emb,
    const float* __restrict__ cls_emb, const int* __restrict__ trg_char)
{
  int m = blockIdx.x, b = m >> 9, s = m & 511;
  int d = threadIdx.x << 2;
  float4* hp = (float4*)(h + (size_t)m * D_ + d);
  if (s == 0) {
    int c = trg_char[b];
    *hp = *(const float4*)(cls_emb + (size_t)c * D_ + d);
  } else {
    int cmd = x[(size_t)(s * B_ + b) * 9];
    float4 v  = *hp;
    float4 ce = *(const float4*)(cmd_emb + (size_t)cmd * D_ + d);
    const float kfac = -0.017988946039f;   // -ln(10000)/512
    int i0 = d >> 1;
    float ang0 = (float)s * expf((float)(2 * i0) * kfac);
    float ang1 = (float)s * expf((float)(2 * (i0 + 1)) * kfac);
    v.x += ce.x + sinf(ang0);
    v.y += ce.y + cosf(ang0);
    v.z += ce.z + sinf(ang1);
    v.w += ce.w + cosf(ang1);
    *hp = v;
  }
}

// ---------------------------------------------------------------------------
__global__ __launch_bounds__(256) void ca_stage(const float* __restrict__ in,
    const float* __restrict__ ca_w, const float* __restrict__ ca_b,
    float* __restrict__ outb, int wsel, int in_is_per_l)
{
  int l = blockIdx.x >> 5, b = blockIdx.x & 31;
  __shared__ float sm[512];
  const float* src = in_is_per_l ? in + ((size_t)l * 32 + b) * 512 : in + (size_t)b * 512;
  for (int i = threadIdx.x; i < 512; i += 256) sm[i] = src[i];
  __syncthreads();
  const float* Wl = ca_w + ((size_t)(l * 4 + wsel)) * 512 * 512;
  const float* bl = ca_b + (l * 4 + wsel) * 512;
  for (int n = threadIdx.x; n < 512; n += 256) {
    const float* wr = Wl + (size_t)n * 512;
    float acc = 0.f;
    for (int k2 = 0; k2 < 512; k2 += 4) {
      float4 w4 = *(const float4*)(wr + k2);
      acc += sm[k2] * w4.x + sm[k2+1] * w4.y + sm[k2+2] * w4.z + sm[k2+3] * w4.w;
    }
    outb[((size_t)l * 32 + b) * 512 + n] = acc + bl[n];
  }
}

__global__ __launch_bounds__(256) void cmd_head(const ushort* __restrict__ xn,
    const float* __restrict__ cw, const float* __restrict__ cb, float* __restrict__ out)
{
  int row  = (blockIdx.x << 2) + (threadIdx.x >> 6);
  int lane = threadIdx.x & 63;
  uint4 raw = *(const uint4*)(xn + (size_t)row * D_ + lane * 8);
  float x0 = bf2f(raw.x & 0xffff), x1 = bf2f(raw.x >> 16);
  float x2 = bf2f(raw.y & 0xffff), x3 = bf2f(raw.y >> 16);
  float x4 = bf2f(raw.z & 0xffff), x5 = bf2f(raw.z >> 16);
  float x6 = bf2f(raw.w & 0xffff), x7 = bf2f(raw.w >> 16);
  #pragma unroll
  for (int n = 0; n < 4; n++) {
    const float* w = cw + n * 512 + lane * 8;
    float4 w0 = *(const float4*)w, w1 = *(const float4*)(w + 4);
    float p = x0*w0.x + x1*w0.y + x2*w0.z + x3*w0.w
            + x4*w1.x + x5*w1.y + x6*w1.z + x7*w1.w;
    #pragma unroll
    for (int m = 1; m < 64; m <<= 1) p += __shfl_xor(p, m);
    if (lane == 0) out[(size_t)row * 4 + n] = p + cb[n];
  }
}

// ---------------------------------------------------------------------------
extern "C" void kernel_launch(void* const* d_in, const int* in_sizes, int n_in,
                              void* d_out, int out_size, void* d_ws, size_t ws_size,
                              hipStream_t stream)
{
  const int*   x          = (const int*)  d_in[0];
  const float* memory     = (const float*)d_in[1];
  const int*   trg_char   = (const int*)  d_in[2];
  const float* cmd_emb    = (const float*)d_in[4];
  const float* arg_emb    = (const float*)d_in[5];
  const float* embed_w    = (const float*)d_in[6];
  const float* embed_b    = (const float*)d_in[7];
  const float* sa_w       = (const float*)d_in[8];
  const float* sa_b       = (const float*)d_in[9];
  const float* ca_w       = (const float*)d_in[10];
  const float* ca_b       = (const float*)d_in[11];
  const float* ff_w1      = (const float*)d_in[12];
  const float* ff_b1      = (const float*)d_in[13];
  const float* ff_w2      = (const float*)d_in[14];
  const float* ff_b2      = (const float*)d_in[15];
  const float* ln_g       = (const float*)d_in[16];
  const float* ln_b       = (const float*)d_in[17];
  const float* fn_g       = (const float*)d_in[18];
  const float* fn_b       = (const float*)d_in[19];
  const float* cls_emb    = (const float*)d_in[20];
  const float* cmd_w      = (const float*)d_in[21];
  const float* cmd_b      = (const float*)d_in[22];
  const float* argf_w     = (const float*)d_in[23];
  const float* argf_b     = (const float*)d_in[24];

  float* out_cmd  = (float*)d_out;
  float* out_args = out_cmd + (size_t)M_ * 4;
  float* out_attn = out_args + (size_t)M_ * 1024;

  const size_t MS = (size_t)M_ * D_;     // 8388608
  float* ws = (float*)d_ws;
  float*  h      = ws;                                   // MS f32
  ushort* qkv_bf = (ushort*)(ws + MS);                   // M*1536 bf16
  ushort* xn_bf  = (ushort*)(ws + MS + 12582912);        // M*512
  ushort* o_bf   = (ushort*)(ws + MS + 16777216);        // M*512
  ushort* tA_bf  = (ushort*)(ws + MS + 20971520);        // M*1024
  ushort* wbf    = (ushort*)(ws + MS + 29360128);
  ushort* sa_wb   = wbf;                                 // 6291456
  ushort* ff1_wb  = wbf + 6291456;                       // 3145728
  ushort* ff2_wb  = wbf + 9437184;                       // 3145728
  ushort* emb_wb  = wbf + 12582912;                      // 524288
  ushort* argf_wb = wbf + 13107200;                      // 524288
  float* vvec   = ws + MS + 29360128 + 6815744;
  float* ca_out = vvec + 6 * 32 * 512;

  dim3 blk256(256), blk128(128), blk512(512);
  dim3 g_g512(4, 128);      // 512 blocks  (%8==0 -> swizzle bijective)
  dim3 g_g1024(8, 128);     // 1024 blocks
  dim3 g_g1536(12, 128);    // 1536 blocks
  dim3 g_ln(M_ / 4);
  dim3 g_attn(4, H_, B_);
  dim3 g_row(M_);

  cvt_bf16<<<dim3(3072), blk256, 0, stream>>>(sa_w,   sa_wb,   786432);
  cvt_bf16<<<dim3(1536), blk256, 0, stream>>>(ff_w1,  ff1_wb,  393216);
  cvt_bf16<<<dim3(1536), blk256, 0, stream>>>(ff_w2,  ff2_wb,  393216);
  cvt_bf16<<<dim3(256),  blk256, 0, stream>>>(embed_w, emb_wb,  65536);
  cvt_bf16<<<dim3(256),  blk256, 0, stream>>>(argf_w, argf_wb,  65536);

  ca_stage<<<dim3(L_ * 32), blk256, 0, stream>>>(memory, ca_w, ca_b, vvec, 2, 0);
  ca_stage<<<dim3(L_ * 32), blk256, 0, stream>>>(vvec, ca_w, ca_b, ca_out, 3, 1);

  gather_emb<<<dim3(8192), blk256, 0, stream>>>(x, arg_emb, tA_bf);
  gemm_mfma<0><<<g_g512, blk256, 0, stream>>>(tA_bf, emb_wb, embed_b, nullptr, h, M_, D_, 1024);
  embed_finish<<<g_row, blk128, 0, stream>>>(h, x, cmd_emb, cls_emb, trg_char);

  for (int l = 0; l < L_; l++) {
    const ushort* saW = sa_wb + (size_t)l * 4 * D_ * D_;
    const float*  saB = sa_b + (size_t)l * 4 * D_;
    ln_bf<<<g_ln, blk256, 0, stream>>>(h, xn_bf, ln_g + (l * 3 + 0) * D_, ln_b + (l * 3 + 0) * D_);
    // fused QKV projection (w0|w1|w2 contiguous rows)
    gemm_mfma<3><<<g_g1536, blk256, 0, stream>>>(xn_bf, saW, saB, nullptr, qkv_bf, M_, 1536, D_);
    if (l == L_ - 1)
      attn_mfma<1><<<g_attn, blk512, 0, stream>>>(qkv_bf, o_bf, out_attn);
    else
      attn_mfma<0><<<g_attn, blk512, 0, stream>>>(qkv_bf, o_bf, nullptr);
    // output projection + residual + cross-attn broadcast (fused)
    gemm_mfma<4><<<g_g512, blk256, 0, stream>>>(o_bf, saW + (size_t)3*D_*D_, saB + 3*D_,
                                                ca_out + (size_t)l * 32 * D_, h, M_, D_, D_);
    ln_bf<<<g_ln, blk256, 0, stream>>>(h, xn_bf, ln_g + (l * 3 + 2) * D_, ln_b + (l * 3 + 2) * D_);
    gemm_mfma<1><<<g_g1024, blk256, 0, stream>>>(xn_bf, ff1_wb + (size_t)l*DFF_*D_, ff_b1 + l*DFF_, nullptr, tA_bf, M_, DFF_, D_);
    gemm_mfma<2><<<g_g512,  blk256, 0, stream>>>(tA_bf, ff2_wb + (size_t)l*D_*DFF_, ff_b2 + l*D_, nullptr, h, M_, D_, DFF_);
  }

  ln_bf<<<g_ln, blk256, 0, stream>>>(h, xn_bf, fn_g, fn_b);
  gemm_mfma<0><<<g_g1024, blk256, 0, stream>>>(xn_bf, argf_wb, argf_b, nullptr, out_args, M_, 1024, D_);
  cmd_head<<<dim3(M_ / 4), blk256, 0, stream>>>(xn_bf, cmd_w, cmd_b, out_cmd);
}